// Round 10
// baseline (72.187 us; speedup 1.0000x reference)
//
#include <hip/hip_runtime.h>

#define B_ 2
#define C_ 121
#define H_ 128
#define W_ 256
#define D_ 48
#define CT 5         // channels per ring chunk; 121 = 24*5 + 1 tail
#define NT 320       // 5 waves: 4 consumers (d-groups) + 1 producer
#define NDY 4        // disparities per consumer thread
#define ZS 3         // d-split: 16 d per block
#define YROW 312     // 48 zero-pad + 256 data + 8 pad (bank start rotates by 24/row)
#define NBUF 4       // ring depth (chunks)

constexpr int HW = H_ * W_;

typedef float f32x4 __attribute__((ext_vector_type(4)));
typedef const void __attribute__((address_space(1)))* gas1_t;
typedef void __attribute__((address_space(3)))* las3_t;

#define VMWAIT(NSTR) asm volatile("s_waitcnt vmcnt(" NSTR ")" ::: "memory")

__launch_bounds__(NT, 4)
__global__ void cost_volume_kernel(const float* __restrict__ xg,
                                   const float* __restrict__ yg,
                                   float* __restrict__ out)
{
    __shared__ __align__(16) float YLS[NBUF][CT][YROW];
    __shared__ int ready;        // producer: chunks [0, ready) are in LDS
    __shared__ int progress[4];  // consumer w: last chunk fully consumed

    const int t  = threadIdx.x;
    const int h  = blockIdx.x;
    const int b  = blockIdx.y;
    const int z  = blockIdx.z;          // owns d in [z*16, z*16+16)
    const int wq = t & 63;
    const int wv = t >> 6;              // 0..3 consumers, 4 producer

    const size_t row0 = (((size_t)b * C_) * H_ + h) * (size_t)W_;
    const float* yrow = yg + row0 + (size_t)wq * 4;

    // init: zero y left pads (only feed masked outputs, but keep defined),
    // ready/progress counters. One barrier in the whole kernel.
    for (int i = t; i < NBUF * CT * 48; i += NT) {
        int s = i / (CT * 48);
        int r = (i % (CT * 48)) / 48;
        YLS[s][r][i % 48] = 0.0f;
    }
    if (t == 0) ready = 0;
    if (wq == 0 && wv < 4) progress[wv] = -1;
    __syncthreads();

    if (wv == 4) {
        // ---------------- producer wave ----------------
        auto issue = [&](int k, int n) {
            for (int cc = 0; cc < n; ++cc)
                __builtin_amdgcn_global_load_lds(
                    (gas1_t)(yrow + (size_t)(k * CT + cc) * HW),
                    (las3_t)&YLS[k & 3][cc][48], 16, 0, 0);
        };
        auto wait_reclaim = [&](int kmin) {   // all consumers past chunk kmin
            for (;;) {
                int m0 = __hip_atomic_load(&progress[0], __ATOMIC_ACQUIRE, __HIP_MEMORY_SCOPE_WORKGROUP);
                int m1 = __hip_atomic_load(&progress[1], __ATOMIC_ACQUIRE, __HIP_MEMORY_SCOPE_WORKGROUP);
                int m2 = __hip_atomic_load(&progress[2], __ATOMIC_ACQUIRE, __HIP_MEMORY_SCOPE_WORKGROUP);
                int m3 = __hip_atomic_load(&progress[3], __ATOMIC_ACQUIRE, __HIP_MEMORY_SCOPE_WORKGROUP);
                if (m0 >= kmin && m1 >= kmin && m2 >= kmin && m3 >= kmin) return;
                __builtin_amdgcn_s_sleep(2);
            }
        };
        auto publish = [&](int v) {
            __hip_atomic_store(&ready, v, __ATOMIC_RELEASE, __HIP_MEMORY_SCOPE_WORKGROUP);
        };

        issue(0, CT); issue(1, CT);      // out: 10
        VMWAIT("5"); publish(1);         // chunk 0 landed
        for (int k = 2; k < 24; ++k) {
            if (k >= NBUF) wait_reclaim(k - NBUF);  // slot k&3 held chunk k-4
            issue(k, CT);                // out: 10
            VMWAIT("5"); publish(k);     // chunk k-1 landed
        }
        wait_reclaim(20);                // tail chunk 24 reuses slot 0 (chunk 20)
        issue(24, 1);
        VMWAIT("1"); publish(24);
        VMWAIT("0"); publish(25);
        return;
    }

    // ---------------- consumer waves ----------------
    const int d0 = z * 16 + wv * NDY;    // multiple of 4
    const int w0 = wq * 4;
    const int bp = w0 - d0 + 44;         // mult of 4; window idx [1,7]; bp+7 <= 303
    const float* xp = xg + row0 + w0;

    float acc[NDY][4] = {};

    auto spin = [&](int k) {             // wait until chunk k available
        while (__hip_atomic_load(&ready, __ATOMIC_ACQUIRE, __HIP_MEMORY_SCOPE_WORKGROUP) <= k)
            __builtin_amdgcn_s_sleep(2);
    };
    auto post = [&](int k) {
        __hip_atomic_store(&progress[wv], k, __ATOMIC_RELEASE, __HIP_MEMORY_SCOPE_WORKGROUP);
    };
    auto chanv = [&](const f32x4 xv, const float* ybase, int ch) {
        float yw[8];
        *(f32x4*)&yw[0] = *(const f32x4*)(ybase + bp);
        *(f32x4*)&yw[4] = *(const f32x4*)(ybase + bp + 4);
        const float xvv[4] = {xv.x, xv.y, xv.z, xv.w};
        #pragma unroll
        for (int jd = 0; jd < NDY; ++jd)
            #pragma unroll
            for (int jw = 0; jw < 4; ++jw)
                acc[jd][jw] += __builtin_fabsf(xvv[jw] - yw[4 + jw - jd]);

        constexpr int KB[9] = {8, 15, 24, 35, 48, 63, 80, 99, 120};
        #pragma unroll
        for (int bi = 0; bi < 9; ++bi) {
            if (ch == KB[bi]) {          // wave-uniform scalar compare
                const float inv = 1.0f / (float)(KB[bi] + 1);
                const size_t obase = (((size_t)b * 9 + bi) * D_) * (size_t)HW
                                   + (size_t)h * W_ + (size_t)w0;
                #pragma unroll
                for (int jd = 0; jd < NDY; ++jd) {
                    const int d = d0 + jd;
                    f32x4 v;
                    v.x = (w0 + 0 >= d) ? acc[jd][0] * inv : 0.0f;
                    v.y = (w0 + 1 >= d) ? acc[jd][1] * inv : 0.0f;
                    v.z = (w0 + 2 >= d) ? acc[jd][2] * inv : 0.0f;
                    v.w = (w0 + 3 >= d) ? acc[jd][3] * inv : 0.0f;
                    *(f32x4*)&out[obase + (size_t)d * HW] = v;
                }
            }
        }
    };

    // x double-buffer in registers, one chunk ahead (static indices only)
    f32x4 xa[CT], xb[CT];
    #pragma unroll
    for (int cc = 0; cc < CT; ++cc)
        xa[cc] = *(const f32x4*)(xp + (size_t)cc * HW);           // chunk 0

    for (int i = 0; i < 12; ++i) {       // chunk pairs (2i, 2i+1)
        const int k0 = 2 * i, k1 = 2 * i + 1;

        spin(k0);
        #pragma unroll
        for (int cc = 0; cc < CT; ++cc)  // prefetch x for k1
            xb[cc] = *(const f32x4*)(xp + (size_t)(k1 * CT + cc) * HW);
        {
            const float* yb = &YLS[k0 & 3][0][0];
            #pragma unroll
            for (int cc = 0; cc < CT; ++cc)
                chanv(xa[cc], yb + cc * YROW, k0 * CT + cc);
        }
        post(k0);

        spin(k1);
        if (i < 11) {
            #pragma unroll
            for (int cc = 0; cc < CT; ++cc)  // prefetch x for chunk 2i+2
                xa[cc] = *(const f32x4*)(xp + (size_t)((k1 + 1) * CT + cc) * HW);
        } else {
            xa[0] = *(const f32x4*)(xp + (size_t)120 * HW);       // tail x
        }
        {
            const float* yb = &YLS[k1 & 3][0][0];
            #pragma unroll
            for (int cc = 0; cc < CT; ++cc)
                chanv(xb[cc], yb + cc * YROW, k1 * CT + cc);
        }
        post(k1);
    }

    // tail: chunk 24 = channel 120 (boundary kk=11), slot 0
    spin(24);
    chanv(xa[0], &YLS[0][0][0], 120);
}

extern "C" void kernel_launch(void* const* d_in, const int* in_sizes, int n_in,
                              void* d_out, int out_size, void* d_ws, size_t ws_size,
                              hipStream_t stream)
{
    const float* x = (const float*)d_in[0];
    const float* y = (const float*)d_in[1];
    float* o = (float*)d_out;
    dim3 grid(H_, B_, ZS);   // z slowest: d-split siblings 256 ids apart -> same XCD
    dim3 block(NT, 1, 1);
    hipLaunchKernelGGL(cost_volume_kernel, grid, block, 0, stream, x, y, o);
}

// Round 11
// 70.921 us; speedup vs baseline: 1.0179x; 1.0179x over previous
//
#include <hip/hip_runtime.h>

#define B_ 2
#define C_ 121
#define H_ 128
#define W_ 256
#define D_ 48
#define NT 256       // 4 waves: 64 w-quads x 4 d-groups
#define NDY 4        // disparities per thread
#define ZS 3         // d-split: 16 d per block

constexpr int HW = H_ * W_;

typedef float f32x4 __attribute__((ext_vector_type(4)));

__launch_bounds__(NT, 3)
__global__ void cost_volume_kernel(const float* __restrict__ xg,
                                   const float* __restrict__ yg,
                                   float* __restrict__ out)
{
    const int t  = threadIdx.x;
    const int h  = blockIdx.x;
    const int b  = blockIdx.y;
    const int z  = blockIdx.z;          // owns d in [z*16, z*16+16)
    const int wq = t & 63;
    const int wv = t >> 6;              // wave id = d-group
    const int d0 = z * 16 + wv * NDY;   // multiple of 4
    const int w0 = wq * 4;

    // y window: needed global w = w0+jw-(d0+jd) = g0 + (4+jw-jd), idx in [1,7].
    // g0 multiple of 4 in [-48,248]. Clamp each aligned quad start to >= 0:
    // clamped lanes only feed outputs with w < d, which the epilogue forces to 0.
    const int g0 = w0 - d0 - 4;
    const int gA = g0     > 0 ? g0     : 0;
    const int gB = g0 + 4 > 0 ? g0 + 4 : 0;

    const size_t row0 = (((size_t)b * C_) * H_ + h) * (size_t)W_;
    const float* xp = xg + row0 + w0;
    const float* pA = yg + row0 + gA;
    const float* pB = yg + row0 + gB;

    float acc[NDY][4] = {};
    f32x4 xq[8], ya[8], yb[8];          // rolling 8-channel pipeline (static idx)

    // ---- consume one channel's registers into acc ----
    auto consume = [&](const f32x4 xv4, const f32x4 ya4, const f32x4 yb4) {
        const float yv[8] = {ya4.x, ya4.y, ya4.z, ya4.w,
                             yb4.x, yb4.y, yb4.z, yb4.w};
        const float xv[4] = {xv4.x, xv4.y, xv4.z, xv4.w};
        #pragma unroll
        for (int jd = 0; jd < NDY; ++jd)
            #pragma unroll
            for (int jw = 0; jw < 4; ++jw)
                acc[jd][jw] += __builtin_fabsf(xv[jw] - yv[4 + jw - jd]);
    };

    // ---- boundary store (bi literal under unroll -> all offsets folded) ----
    const size_t ob0 = ((size_t)b * 9 * D_) * (size_t)HW + (size_t)h * W_ + w0
                     + (size_t)d0 * HW;
    auto store_b = [&](int bi) {
        constexpr int KB[9] = {8, 15, 24, 35, 48, 63, 80, 99, 120};
        const float inv = 1.0f / (float)(KB[bi] + 1);
        float* op = out + ob0 + (size_t)bi * D_ * HW;
        #pragma unroll
        for (int jd = 0; jd < NDY; ++jd) {
            const int d = d0 + jd;
            f32x4 v;
            v.x = (w0 + 0 >= d) ? acc[jd][0] * inv : 0.0f;
            v.y = (w0 + 1 >= d) ? acc[jd][1] * inv : 0.0f;
            v.z = (w0 + 2 >= d) ? acc[jd][2] * inv : 0.0f;
            v.w = (w0 + 3 >= d) ? acc[jd][3] * inv : 0.0f;
            *(f32x4*)(op + (size_t)jd * HW) = v;
        }
    };

    // ---- prologue: channels 0..7 in flight (24 loads) ----
    #pragma unroll
    for (int j = 0; j < 8; ++j) {
        const size_t off = (size_t)j * HW;
        xq[j] = *(const f32x4*)(xp + off);
        ya[j] = *(const f32x4*)(pA + off);
        yb[j] = *(const f32x4*)(pB + off);
    }

    // ---- main: g = 0..13, consume c = 8g+j, prefetch c+8 (max 119) ----
    // boundaries c=8g+j: 8=(1,0) 15=(1,7) 24=(3,0) 35=(4,3) 48=(6,0)
    //                    63=(7,7) 80=(10,0) 99=(12,3); 120 in tail.
    for (int g = 0; g < 14; ++g) {
        #pragma unroll
        for (int j = 0; j < 8; ++j) {
            consume(xq[j], ya[j], yb[j]);
            if (j == 0) {
                if (g == 1)  store_b(0);
                if (g == 3)  store_b(2);
                if (g == 6)  store_b(4);
                if (g == 10) store_b(6);
            }
            if (j == 3) {
                if (g == 4)  store_b(3);
                if (g == 12) store_b(7);
            }
            if (j == 7) {
                if (g == 1)  store_b(1);
                if (g == 7)  store_b(5);
            }
            const size_t off = (size_t)(8 * g + j + 8) * HW;   // <= 119*HW
            xq[j] = *(const f32x4*)(xp + off);
            ya[j] = *(const f32x4*)(pA + off);
            yb[j] = *(const f32x4*)(pB + off);
        }
    }

    // ---- tail: slots hold c=112..119; c=120 loaded early, then consumed ----
    {
        const size_t off = (size_t)120 * HW;
        const f32x4 xt  = *(const f32x4*)(xp + off);
        const f32x4 yat = *(const f32x4*)(pA + off);
        const f32x4 ybt = *(const f32x4*)(pB + off);
        #pragma unroll
        for (int j = 0; j < 8; ++j)
            consume(xq[j], ya[j], yb[j]);       // c = 112..119, no boundaries
        consume(xt, yat, ybt);                   // c = 120
        store_b(8);
    }
}

extern "C" void kernel_launch(void* const* d_in, const int* in_sizes, int n_in,
                              void* d_out, int out_size, void* d_ws, size_t ws_size,
                              hipStream_t stream)
{
    const float* x = (const float*)d_in[0];
    const float* y = (const float*)d_in[1];
    float* o = (float*)d_out;
    dim3 grid(H_, B_, ZS);   // z slowest: d-split siblings 256 ids apart -> same XCD
    dim3 block(NT, 1, 1);
    hipLaunchKernelGGL(cost_volume_kernel, grid, block, 0, stream, x, y, o);
}